// Round 1
// baseline (17.263 us; speedup 1.0000x reference)
//
#include <hip/hip_runtime.h>
#include <math.h>

#define BATCH 1024
#define SEQ   200
#define DIM   128

__global__ __launch_bounds__(256) void dft_layer_kernel(
    const int* __restrict__ seqs,
    const float* __restrict__ emb,
    float* __restrict__ out)
{
    const int b   = blockIdx.x;
    const int tid = threadIdx.x;

    __shared__ int   s_seq[SEQ];
    __shared__ float s_mag[SEQ];
    __shared__ int   s_match[SEQ];
    __shared__ int   s_cnt[2];        // [0]=L, [1]=M
    __shared__ float s_sum;
    __shared__ float s_part[8][DIM];  // 8 s-groups x 128 floats

    if (tid < 2)  s_cnt[tid] = 0;
    if (tid == 0) s_sum = 0.0f;
    if (tid < SEQ) s_seq[tid] = seqs[b * SEQ + tid];
    __syncthreads();

    // L = number of nonzero tokens (contiguous at front)
    bool nz = (tid < SEQ) && (s_seq[tid] != 0);
    unsigned long long bal = __ballot(nz);
    if ((tid & 63) == 0) atomicAdd(&s_cnt[0], __popcll(bal));
    __syncthreads();

    const int L    = s_cnt[0];
    const int last = s_seq[L - 1];

    // collect positions where token == last (these are the nonzeros of `binary`)
    if (tid < L && s_seq[tid] == last) {
        int idx = atomicAdd(&s_cnt[1], 1);
        s_match[idx] = tid;
    }
    __syncthreads();
    const int   M  = s_cnt[1];
    const float Lf = (float)L;

    // per-k DFT magnitude over the M nonzeros; keep k < L-1, zero elsewhere
    float mag = 0.0f;
    if (tid < SEQ) {
        if (tid < L - 1) {
            float re = 0.0f, im = 0.0f;
            const float kf = (float)tid;
            for (int m = 0; m < M; ++m) {
                float kn    = kf * (float)s_match[m];
                float theta = (-6.2831855f * kn) / Lf;  // match ref op order
                float sv, cv;
                sincosf(theta, &sv, &cv);
                re += cv;
                im += sv;
            }
            mag = sqrtf(re * re + im * im);
        }
        s_mag[tid] = mag;
    }
    // block-reduce sum of mag
    float v = mag;
    #pragma unroll
    for (int o = 32; o > 0; o >>= 1) v += __shfl_down(v, o, 64);
    if ((tid & 63) == 0) atomicAdd(&s_sum, v);
    __syncthreads();
    const float invSum = 1.0f / s_sum;

    // out[b,:] = invSum * sum_{s=1}^{L-1} mag[s-1] * emb[b,s,:]
    // 8 s-groups (g) x 32 lanes each handling one float4 chunk of the row
    const int c4 = tid & 31;         // float4 chunk index within row (0..31)
    const int g  = tid >> 5;         // s-group 0..7
    const float4* ebase = (const float4*)(emb + (size_t)b * SEQ * DIM);
    float4 acc = make_float4(0.f, 0.f, 0.f, 0.f);
    for (int s = 1 + g; s < L; s += 8) {
        float  w = s_mag[s - 1];
        float4 e = ebase[s * 32 + c4];
        acc.x += w * e.x; acc.y += w * e.y; acc.z += w * e.z; acc.w += w * e.w;
    }
    {
        float* p = &s_part[g][c4 << 2];
        p[0] = acc.x; p[1] = acc.y; p[2] = acc.z; p[3] = acc.w;
    }
    __syncthreads();
    if (tid < DIM) {
        float r = 0.0f;
        #pragma unroll
        for (int gg = 0; gg < 8; ++gg) r += s_part[gg][tid];
        out[(size_t)b * DIM + tid] = r * invSum;
    }
}

extern "C" void kernel_launch(void* const* d_in, const int* in_sizes, int n_in,
                              void* d_out, int out_size, void* d_ws, size_t ws_size,
                              hipStream_t stream) {
    const int*   seqs = (const int*)d_in[0];
    const float* emb  = (const float*)d_in[1];
    float*       out  = (float*)d_out;
    dft_layer_kernel<<<BATCH, 256, 0, stream>>>(seqs, emb, out);
}